// Round 12
// baseline (2443.833 us; speedup 1.0000x reference)
//
#include <hip/hip_runtime.h>
#include <hip/hip_bf16.h>
#include <stdint.h>

#define QMAXF 127.0f

typedef __attribute__((ext_vector_type(4))) float f32x4;
typedef __attribute__((ext_vector_type(4))) int i32x4;

typedef __attribute__((address_space(1))) void gbl_void;
typedef __attribute__((address_space(3))) void lds_void;

__device__ __forceinline__ void gload_lds16(const void* g, void* l) {
    __builtin_amdgcn_global_load_lds((const gbl_void*)g, (lds_void*)l, 16, 0, 0);
}

// ---------------------------------------------------------------------------
// Kernel 1: per-token, per-128-col-group INT8 quant of activations.
// ---------------------------------------------------------------------------
__global__ __launch_bounds__(256) void qd_x_kernel(const float* __restrict__ x,
                                                   char* __restrict__ qx,
                                                   float* __restrict__ sxT,
                                                   long ngroups, int nkb, int T) {
    long gw = ((long)blockIdx.x * blockDim.x + threadIdx.x) >> 6;
    int lane = threadIdx.x & 63;
    if (gw >= ngroups) return;

    float2 v = *(reinterpret_cast<const float2*>(x) + gw * 64 + lane);
    float a = fmaxf(fabsf(v.x), fabsf(v.y));
#pragma unroll
    for (int off = 32; off; off >>= 1) a = fmaxf(a, __shfl_xor(a, off));

    float scale = a > 0.f ? a / QMAXF : 1.f;
    int q0 = (int)fminf(fmaxf(rintf(v.x / scale), -QMAXF), QMAXF);
    int q1 = (int)fminf(fmaxf(rintf(v.y / scale), -QMAXF), QMAXF);
    unsigned short packed = (unsigned short)((q0 & 0xFF) | ((q1 & 0xFF) << 8));
    reinterpret_cast<unsigned short*>(qx)[gw * 64 + lane] = packed;

    if (lane == 0) {
        int t = (int)(gw / nkb), kb = (int)(gw - (long)t * nkb);
        sxT[(size_t)kb * T + t] = scale;
    }
}

// ---------------------------------------------------------------------------
// Kernel 2: 128x128 blockwise INT8 quant of weights.
// ---------------------------------------------------------------------------
__global__ __launch_bounds__(256) void qd_w_kernel(const float* __restrict__ w,
                                                   char* __restrict__ qw,
                                                   float* __restrict__ sw,
                                                   int K, int nkb) {
    int kb = blockIdx.x, ob = blockIdx.y;
    size_t base = (size_t)ob * 128 * K + (size_t)kb * 128;
    int t = threadIdx.x;

    float4 v[16];
    float a = 0.f;
#pragma unroll
    for (int i = 0; i < 16; i++) {
        int f = i * 256 + t;
        int row = f >> 5, c4 = f & 31;
        v[i] = *reinterpret_cast<const float4*>(w + base + (size_t)row * K + c4 * 4);
        a = fmaxf(a, fmaxf(fmaxf(fabsf(v[i].x), fabsf(v[i].y)),
                           fmaxf(fabsf(v[i].z), fabsf(v[i].w))));
    }
#pragma unroll
    for (int off = 32; off; off >>= 1) a = fmaxf(a, __shfl_xor(a, off));

    __shared__ float red[4];
    if ((t & 63) == 0) red[t >> 6] = a;
    __syncthreads();
    a = fmaxf(fmaxf(red[0], red[1]), fmaxf(red[2], red[3]));

    float scale = a > 0.f ? a / QMAXF : 1.f;
    if (t == 0) sw[(size_t)ob * nkb + kb] = scale;
#pragma unroll
    for (int i = 0; i < 16; i++) {
        int f = i * 256 + t;
        int row = f >> 5, c4 = f & 31;
        int q0 = (int)fminf(fmaxf(rintf(v[i].x / scale), -QMAXF), QMAXF);
        int q1 = (int)fminf(fmaxf(rintf(v[i].y / scale), -QMAXF), QMAXF);
        int q2 = (int)fminf(fmaxf(rintf(v[i].z / scale), -QMAXF), QMAXF);
        int q3 = (int)fminf(fmaxf(rintf(v[i].w / scale), -QMAXF), QMAXF);
        unsigned int p = (q0 & 0xFF) | ((q1 & 0xFF) << 8) | ((q2 & 0xFF) << 16) |
                         ((unsigned int)(q3 & 0xFF) << 24);
        *reinterpret_cast<unsigned int*>(qw + base + (size_t)row * K + c4 * 4) = p;
    }
}

// ---------------------------------------------------------------------------
// Kernel 3: R6 i8 GEMM (654 us, verified), templateized for ABLATION.
// V bits: 1=per-iter LDS reads, 2=MFMA, 4=FIX(+sx/sw loads), 8=per-iter stage.
// Variants all run full-size and write d_out; final FULL dispatch overwrites
// with the correct result. asm sinks keep ablated values live (rule 17).
// ---------------------------------------------------------------------------
#define GBM 256
#define GBN 256
#define SLOT_BY 65536          // 64 KB: A 32K + B 32K (int8)

#define BAR()                              \
    do {                                   \
        asm volatile("" ::: "memory");     \
        __builtin_amdgcn_s_barrier();      \
        asm volatile("" ::: "memory");     \
    } while (0)
#define WAITL0()                                          \
    do {                                                  \
        asm volatile("s_waitcnt lgkmcnt(0)" ::: "memory");\
        __builtin_amdgcn_sched_barrier(0);                \
    } while (0)
#define WAITV0() asm volatile("s_waitcnt vmcnt(0)" ::: "memory")
#define SINKV(x) asm volatile("" :: "v"((x)[0]), "v"((x)[1]), "v"((x)[2]), "v"((x)[3]))

template <int V>
__device__ __forceinline__ void gemm_body(
    const char* __restrict__ Aq, const char* __restrict__ Bq,
    const float* __restrict__ sxT, const float* __restrict__ swp,
    const float* __restrict__ bias, float* __restrict__ C,
    int M, int N, int K) {
    constexpr bool DO_RD = (V & 1) != 0;
    constexpr bool DO_MMA = (V & 2) != 0;
    constexpr bool DO_FIX = (V & 4) != 0;
    constexpr bool DO_STG = (V & 8) != 0;

    __shared__ alignas(16) unsigned char lds8[2 * SLOT_BY];  // 128 KiB

    int nTm = M >> 8, nTn = N >> 8;
    int nwg = gridDim.x, wg = blockIdx.x;
    int mt, nt;
    int mper = nTm >> 3;
    if ((nTm & 7) == 0 && mper > 0 && (32 % mper) == 0) {
        int x = wg & 7, j = wg >> 3;
        int G = 32 / mper;
        int wsz = mper * G;
        int fullw = nTn / G;
        int jfull = fullw * wsz;
        int g, r, width;
        if (j < jfull) { g = j / wsz; r = j - g * wsz; width = G; }
        else { g = fullw; r = j - jfull; width = nTn - fullw * G; }
        mt = x * mper + r / width;
        nt = g * G + r % width;
    } else {
        int swz = (nwg & 7) ? wg : ((wg & 7) * (nwg >> 3) + (wg >> 3));
        mt = swz / nTn; nt = swz - mt * nTn;
    }

    int t = threadIdx.x, wid = t >> 6, lane = t & 63;
    int wm = wid >> 2, wn = wid & 3;   // 2x4 wave grid; wave tile 128x64
    int lr = lane & 15, lq = lane >> 4;
    int nkb = K >> 7;

    const char* Abase = Aq + (size_t)mt * GBM * K;
    const char* Bbase = Bq + (size_t)nt * GBN * K;

    int cid0 = t, cid1 = 512 + t;
    int rl0 = cid0 >> 3, rl1 = cid1 >> 3;
    int gc0 = ((cid0 & 7) ^ (rl0 & 7)) * 16, gc1 = ((cid1 & 7) ^ (rl1 & 7)) * 16;

    auto STAGE = [&](int slot, int mat, int half, int kb) {
        const char* gb = (mat ? Bbase : Abase) + (size_t)(half * 128) * K + kb;
        unsigned char* db = lds8 + slot * SLOT_BY + mat * 32768 + half * 16384;
        gload_lds16(gb + (size_t)rl0 * K + gc0, db + cid0 * 16);
        gload_lds16(gb + (size_t)rl1 * K + gc1, db + cid1 * 16);
    };

    int offA[4][2], offB[2][2];
#pragma unroll
    for (int m = 0; m < 4; m++) {
        int row = wm * 128 + m * 16 + lr;
#pragma unroll
        for (int kk = 0; kk < 2; kk++)
            offA[m][kk] = row * 128 + (((kk * 4 + lq) ^ (lr & 7)) << 4);
    }
#pragma unroll
    for (int n = 0; n < 2; n++) {
        int row = wn * 64 + n * 16 + lr;
#pragma unroll
        for (int kk = 0; kk < 2; kk++)
            offB[n][kk] = 32768 + row * 128 + (((kk * 4 + lq) ^ (lr & 7)) << 4);
    }

    f32x4 facc[8][4];
#pragma unroll
    for (int m = 0; m < 8; m++)
#pragma unroll
        for (int n = 0; n < 4; n++) facc[m][n] = (f32x4){0.f, 0.f, 0.f, 0.f};

    i32x4 a[4][2], b[2][2], ia[4][2];
    f32x4 sx4[4];
    float swq = 0.f;
    i32x4 zc = (i32x4){0, 0, 0, 0};

    auto LDA = [&](int slot, int mq) {
        const unsigned char* base = lds8 + slot * SLOT_BY + mq * 8192;
#pragma unroll
        for (int m = 0; m < 4; m++)
#pragma unroll
            for (int kk = 0; kk < 2; kk++)
                a[m][kk] = *reinterpret_cast<const i32x4*>(base + offA[m][kk]);
    };
    auto LDB = [&](int slot, int nq) {
        const unsigned char* base = lds8 + slot * SLOT_BY + nq * 4096;
#pragma unroll
        for (int n = 0; n < 2; n++)
#pragma unroll
            for (int kk = 0; kk < 2; kk++)
                b[n][kk] = *reinterpret_cast<const i32x4*>(base + offB[n][kk]);
    };
    auto MMA = [&]() {
        __builtin_amdgcn_s_setprio(1);
#pragma unroll
        for (int m = 0; m < 4; m++)
#pragma unroll
            for (int n = 0; n < 2; n++) {
                ia[m][n] = __builtin_amdgcn_mfma_i32_16x16x64_i8(a[m][0], b[n][0],
                                                                 zc, 0, 0, 0);
                ia[m][n] = __builtin_amdgcn_mfma_i32_16x16x64_i8(a[m][1], b[n][1],
                                                                 ia[m][n], 0, 0, 0);
            }
        __builtin_amdgcn_s_setprio(0);
    };
    auto FIX = [&](int mq, int nq) {
#pragma unroll
        for (int m = 0; m < 4; m++) {
            f32x4 s = sx4[m] * swq;
#pragma unroll
            for (int n = 0; n < 2; n++) {
                f32x4 cv;
#pragma unroll
                for (int r = 0; r < 4; r++) cv[r] = (float)ia[m][n][r];
                facc[mq * 4 + m][nq * 2 + n] += cv * s;
            }
        }
    };
    auto SINK_IA = [&]() {
#pragma unroll
        for (int m = 0; m < 4; m++) { SINKV(ia[m][0]); SINKV(ia[m][1]); }
    };
    auto SINK_A = [&]() {
#pragma unroll
        for (int m = 0; m < 4; m++) { SINKV(a[m][0]); SINKV(a[m][1]); }
    };
    auto SINK_B = [&]() { SINKV(b[0][0]); SINKV(b[0][1]); SINKV(b[1][0]); SINKV(b[1][1]); };

    int sxrow0 = mt * GBM + wm * 128 + lq * 4;
    auto LDSX = [&](int i, int mq) {
#pragma unroll
        for (int m = 0; m < 4; m++)
            sx4[m] = *reinterpret_cast<const f32x4*>(
                sxT + (size_t)i * M + sxrow0 + mq * 64 + m * 16);
    };
    int swbase = (nt * 2 + (wn >> 1)) * nkb;

    // Prologue: slot0 <- K-block 0.
    STAGE(0, 0, 0, 0); STAGE(0, 0, 1, 0);
    STAGE(0, 1, 0, 0); STAGE(0, 1, 1, 0);
    WAITV0();
    BAR();
    if constexpr (!DO_RD) {  // NOREADS: load operands once, reuse every iter
        LDA(0, 0); LDB(0, 0);
        WAITL0();
    }

    for (int i = 0; i < nkb; ++i) {
        int p = DO_STG ? (i & 1) : 0;
        int q = p ^ 1;
        int knext = (i + 1 < nkb ? i + 1 : i) * 128;
        if constexpr (!DO_RD) {  // opaque zero: blocks LICM of loop-invariant MFMA
            int zz = 0;
            asm volatile("" : "+v"(zz));
            zc = (i32x4){zz, zz, zz, zz};
        }

        // ph1: Q(0,0)
        if constexpr (DO_RD) { LDA(p, 0); LDB(p, 0); }
        if constexpr (DO_STG) { STAGE(q, 0, 0, knext); STAGE(q, 1, 0, knext); }
        if constexpr (DO_FIX) { LDSX(i, 0); swq = swp[swbase + i]; }
        BAR();
        if constexpr (DO_RD) WAITL0();
        if constexpr (DO_MMA) { MMA(); if constexpr (DO_FIX) FIX(0, 0); else SINK_IA(); }
        else if constexpr (DO_RD) { SINK_A(); SINK_B(); }
        BAR();
        // ph2: Q(0,1)
        if constexpr (DO_RD) LDB(p, 1);
        if constexpr (DO_STG) { STAGE(q, 0, 1, knext); STAGE(q, 1, 1, knext); }
        BAR();
        if constexpr (DO_RD) WAITL0();
        if constexpr (DO_MMA) { MMA(); if constexpr (DO_FIX) FIX(0, 1); else SINK_IA(); }
        else if constexpr (DO_RD) SINK_B();
        BAR();
        // ph3: Q(1,1)
        if constexpr (DO_RD) LDA(p, 1);
        if constexpr (DO_FIX) LDSX(i, 1);
        BAR();
        if constexpr (DO_RD) WAITL0();
        if constexpr (DO_MMA) { MMA(); if constexpr (DO_FIX) FIX(1, 1); else SINK_IA(); }
        else if constexpr (DO_RD) SINK_A();
        BAR();
        // ph4: Q(1,0)
        if constexpr (DO_RD) LDB(p, 0);
        BAR();
        if constexpr (DO_RD) WAITL0();
        if constexpr (DO_MMA) { MMA(); if constexpr (DO_FIX) FIX(1, 0); else SINK_IA(); }
        else if constexpr (DO_RD) SINK_B();
        if constexpr (DO_STG) WAITV0();
        BAR();
    }

    // Epilogue: bias + store.
    float bvv[4];
#pragma unroll
    for (int n = 0; n < 4; n++) bvv[n] = bias[nt * GBN + wn * 64 + n * 16 + lr];
#pragma unroll
    for (int m = 0; m < 8; m++) {
#pragma unroll
        for (int r = 0; r < 4; r++) {
            size_t row = (size_t)(mt * GBM + wm * 128 + m * 16 + lq * 4 + r);
            float* Crow = C + row * N + nt * GBN + wn * 64 + lr;
#pragma unroll
            for (int n = 0; n < 4; n++) Crow[n * 16] = facc[m][n][r] + bvv[n];
        }
    }
}

#define GEMM_ARGS const char* Aq, const char* Bq, const float* sxT, \
                  const float* swp, const float* bias, float* C, int M, int N, int K

__global__ __launch_bounds__(512, 1) void gemm_ab_nofix(GEMM_ARGS) {
    gemm_body<1 | 2 | 8>(Aq, Bq, sxT, swp, bias, C, M, N, K);
}
__global__ __launch_bounds__(512, 1) void gemm_ab_nomma(GEMM_ARGS) {
    gemm_body<1 | 8>(Aq, Bq, sxT, swp, bias, C, M, N, K);
}
__global__ __launch_bounds__(512, 1) void gemm_ab_nords(GEMM_ARGS) {
    gemm_body<2 | 4 | 8>(Aq, Bq, sxT, swp, bias, C, M, N, K);
}
__global__ __launch_bounds__(512, 1) void gemm_ab_nostg(GEMM_ARGS) {
    gemm_body<1 | 2 | 4>(Aq, Bq, sxT, swp, bias, C, M, N, K);
}
__global__ __launch_bounds__(512, 1) void gemm_full(GEMM_ARGS) {
    gemm_body<15>(Aq, Bq, sxT, swp, bias, C, M, N, K);
}

extern "C" void kernel_launch(void* const* d_in, const int* in_sizes, int n_in,
                              void* d_out, int out_size, void* d_ws, size_t ws_size,
                              hipStream_t stream) {
    const float* x = (const float*)d_in[0];
    const float* w = (const float*)d_in[1];
    const float* bias = (const float*)d_in[2];
    float* y = (float*)d_out;

    int O = in_sizes[2];          // 11008
    int K = in_sizes[1] / O;      // 4096
    int T = in_sizes[0] / K;      // 8192 tokens
    int nkb = K / 128;            // 32

    char* qx = (char*)d_ws;
    size_t off = ((size_t)T * K + 255) & ~(size_t)255;
    char* qw = (char*)d_ws + off;
    off += ((size_t)O * K + 255) & ~(size_t)255;
    float* sxT = (float*)((char*)d_ws + off);
    off += ((size_t)nkb * T * 4 + 255) & ~(size_t)255;
    float* sw = (float*)((char*)d_ws + off);

    long ngroups = (long)T * nkb;
    qd_x_kernel<<<dim3((unsigned)((ngroups + 3) / 4)), dim3(256), 0, stream>>>(
        x, qx, sxT, ngroups, nkb, T);
    qd_w_kernel<<<dim3(nkb, O / 128), dim3(256), 0, stream>>>(w, qw, sw, K, nkb);

    int grid = (T / 256) * (O / 256);
    // Ablation dispatches (write garbage/partial to y; overwritten by gemm_full).
    gemm_ab_nofix<<<dim3(grid), dim3(512), 0, stream>>>(qx, qw, sxT, sw, bias, y, T, O, K);
    gemm_ab_nomma<<<dim3(grid), dim3(512), 0, stream>>>(qx, qw, sxT, sw, bias, y, T, O, K);
    gemm_ab_nords<<<dim3(grid), dim3(512), 0, stream>>>(qx, qw, sxT, sw, bias, y, T, O, K);
    gemm_ab_nostg<<<dim3(grid), dim3(512), 0, stream>>>(qx, qw, sxT, sw, bias, y, T, O, K);
    // Final correct result.
    gemm_full<<<dim3(grid), dim3(512), 0, stream>>>(qx, qw, sxT, sw, bias, y, T, O, K);
}

// Round 13
// 746.301 us; speedup vs baseline: 3.2746x; 3.2746x over previous
//
#include <hip/hip_runtime.h>
#include <hip/hip_bf16.h>
#include <stdint.h>

#define QMAXF 127.0f

typedef __attribute__((ext_vector_type(4))) float f32x4;
typedef __attribute__((ext_vector_type(4))) int i32x4;

typedef __attribute__((address_space(1))) void gbl_void;
typedef __attribute__((address_space(3))) void lds_void;

__device__ __forceinline__ void gload_lds16(const void* g, void* l) {
    __builtin_amdgcn_global_load_lds((const gbl_void*)g, (lds_void*)l, 16, 0, 0);
}

// ---------------------------------------------------------------------------
// Kernel 1: per-token, per-128-col-group INT8 quant of activations.
// ---------------------------------------------------------------------------
__global__ __launch_bounds__(256) void qd_x_kernel(const float* __restrict__ x,
                                                   char* __restrict__ qx,
                                                   float* __restrict__ sxT,
                                                   long ngroups, int nkb, int T) {
    long gw = ((long)blockIdx.x * blockDim.x + threadIdx.x) >> 6;
    int lane = threadIdx.x & 63;
    if (gw >= ngroups) return;

    float2 v = *(reinterpret_cast<const float2*>(x) + gw * 64 + lane);
    float a = fmaxf(fabsf(v.x), fabsf(v.y));
#pragma unroll
    for (int off = 32; off; off >>= 1) a = fmaxf(a, __shfl_xor(a, off));

    float scale = a > 0.f ? a / QMAXF : 1.f;
    int q0 = (int)fminf(fmaxf(rintf(v.x / scale), -QMAXF), QMAXF);
    int q1 = (int)fminf(fmaxf(rintf(v.y / scale), -QMAXF), QMAXF);
    unsigned short packed = (unsigned short)((q0 & 0xFF) | ((q1 & 0xFF) << 8));
    reinterpret_cast<unsigned short*>(qx)[gw * 64 + lane] = packed;

    if (lane == 0) {
        int t = (int)(gw / nkb), kb = (int)(gw - (long)t * nkb);
        sxT[(size_t)kb * T + t] = scale;
    }
}

// ---------------------------------------------------------------------------
// Kernel 2: 128x128 blockwise INT8 quant of weights.
// ---------------------------------------------------------------------------
__global__ __launch_bounds__(256) void qd_w_kernel(const float* __restrict__ w,
                                                   char* __restrict__ qw,
                                                   float* __restrict__ sw,
                                                   int K, int nkb) {
    int kb = blockIdx.x, ob = blockIdx.y;
    size_t base = (size_t)ob * 128 * K + (size_t)kb * 128;
    int t = threadIdx.x;

    float4 v[16];
    float a = 0.f;
#pragma unroll
    for (int i = 0; i < 16; i++) {
        int f = i * 256 + t;
        int row = f >> 5, c4 = f & 31;
        v[i] = *reinterpret_cast<const float4*>(w + base + (size_t)row * K + c4 * 4);
        a = fmaxf(a, fmaxf(fmaxf(fabsf(v[i].x), fabsf(v[i].y)),
                           fmaxf(fabsf(v[i].z), fabsf(v[i].w))));
    }
#pragma unroll
    for (int off = 32; off; off >>= 1) a = fmaxf(a, __shfl_xor(a, off));

    __shared__ float red[4];
    if ((t & 63) == 0) red[t >> 6] = a;
    __syncthreads();
    a = fmaxf(fmaxf(red[0], red[1]), fmaxf(red[2], red[3]));

    float scale = a > 0.f ? a / QMAXF : 1.f;
    if (t == 0) sw[(size_t)ob * nkb + kb] = scale;
#pragma unroll
    for (int i = 0; i < 16; i++) {
        int f = i * 256 + t;
        int row = f >> 5, c4 = f & 31;
        int q0 = (int)fminf(fmaxf(rintf(v[i].x / scale), -QMAXF), QMAXF);
        int q1 = (int)fminf(fmaxf(rintf(v[i].y / scale), -QMAXF), QMAXF);
        int q2 = (int)fminf(fmaxf(rintf(v[i].z / scale), -QMAXF), QMAXF);
        int q3 = (int)fminf(fmaxf(rintf(v[i].w / scale), -QMAXF), QMAXF);
        unsigned int p = (q0 & 0xFF) | ((q1 & 0xFF) << 8) | ((q2 & 0xFF) << 16) |
                         ((unsigned int)(q3 & 0xFF) << 24);
        *reinterpret_cast<unsigned int*>(qw + base + (size_t)row * K + c4 * 4) = p;
    }
}

// ---------------------------------------------------------------------------
// Kernel 3: exact INT8 GEMM, 256x256 tile, 8 waves, double-buffered (128 KB),
// ONE barrier per K128 iter (hazard analysis: reads<-slot p, writes->slot q;
// (a) q-writes after all q-reads: prev lgkm0s + BAR; (b) p-reads after
// p-writes complete: prev iter's vmcnt(0) + BAR). Per iter:
//   BAR -> scales -> 8 stages -> dsA0+dsB(16 b128) -> lgkm0 -> vmcnt(8)
//   [forces scales, stages fly] -> MFMA+FIX mq0 -> dsA1+sxO -> lgkm0 ->
//   vmcnt(0) [stages had ~full phase] -> MFMA+FIX mq1.
// B fragments held in registers across both halves (24 b128/iter vs R6's 32).
// ---------------------------------------------------------------------------
#define GBM 256
#define GBN 256
#define SLOT_BY 65536          // 64 KB: A 32K + B 32K (int8)

#define BAR()                              \
    do {                                   \
        asm volatile("" ::: "memory");     \
        __builtin_amdgcn_s_barrier();      \
        asm volatile("" ::: "memory");     \
    } while (0)
#define WAITL0()                                          \
    do {                                                  \
        asm volatile("s_waitcnt lgkmcnt(0)" ::: "memory");\
        __builtin_amdgcn_sched_barrier(0);                \
    } while (0)
#define WAITV(n) asm volatile("s_waitcnt vmcnt(" #n ")" ::: "memory")
#define SCHED0() __builtin_amdgcn_sched_barrier(0)

__global__ __launch_bounds__(512, 1) void gemm_i8_kernel(
    const char* __restrict__ Aq,    // [M,K] int8
    const char* __restrict__ Bq,    // [N,K] int8
    const float* __restrict__ sxT,  // [K/128][M]
    const float* __restrict__ swp,  // [N/128][K/128]
    const float* __restrict__ bias,
    float* __restrict__ C,          // [M,N] f32
    int M, int N, int K) {
    __shared__ alignas(16) unsigned char lds8[2 * SLOT_BY];  // 128 KiB

    int nTm = M >> 8, nTn = N >> 8;
    int nwg = gridDim.x, wg = blockIdx.x;
    int mt, nt;
    int mper = nTm >> 3;
    if ((nTm & 7) == 0 && mper > 0 && (32 % mper) == 0) {
        // XCD-aware 2D window (R5): 32 co-resident blocks/XCD share panels.
        int x = wg & 7, j = wg >> 3;
        int G = 32 / mper;
        int wsz = mper * G;
        int fullw = nTn / G;
        int jfull = fullw * wsz;
        int g, r, width;
        if (j < jfull) { g = j / wsz; r = j - g * wsz; width = G; }
        else { g = fullw; r = j - jfull; width = nTn - fullw * G; }
        mt = x * mper + r / width;
        nt = g * G + r % width;
    } else {
        int swz = (nwg & 7) ? wg : ((wg & 7) * (nwg >> 3) + (wg >> 3));
        mt = swz / nTn; nt = swz - mt * nTn;
    }

    int t = threadIdx.x, wid = t >> 6, lane = t & 63;
    int wm = wid >> 2, wn = wid & 3;   // 2x4 wave grid; wave tile 128x64
    int lr = lane & 15, lq = lane >> 4;
    int nkb = K >> 7;

    const char* Abase = Aq + (size_t)mt * GBM * K;
    const char* Bbase = Bq + (size_t)nt * GBN * K;

    // Staging (verified R6): involution swizzle, logical chunk = phys^(row&7).
    int cid0 = t, cid1 = 512 + t;
    int rl0 = cid0 >> 3, rl1 = cid1 >> 3;
    int gc0 = ((cid0 & 7) ^ (rl0 & 7)) * 16, gc1 = ((cid1 & 7) ^ (rl1 & 7)) * 16;

    auto STAGE8 = [&](int slot, int kb) {
        unsigned char* sb = lds8 + slot * SLOT_BY;
#pragma unroll
        for (int half = 0; half < 2; half++) {
            const char* ga = Abase + (size_t)(half * 128) * K + kb;
            const char* gb = Bbase + (size_t)(half * 128) * K + kb;
            unsigned char* da = sb + half * 16384;
            unsigned char* db = sb + 32768 + half * 16384;
            gload_lds16(ga + (size_t)rl0 * K + gc0, da + cid0 * 16);
            gload_lds16(ga + (size_t)rl1 * K + gc1, da + cid1 * 16);
            gload_lds16(gb + (size_t)rl0 * K + gc0, db + cid0 * 16);
            gload_lds16(gb + (size_t)rl1 * K + gc1, db + cid1 * 16);
        }
    };

    // Fragment read offsets (verified R6).
    int offA[4][2], offB[4][2];
#pragma unroll
    for (int m = 0; m < 4; m++) {
        int row = wm * 128 + m * 16 + lr;
#pragma unroll
        for (int kk = 0; kk < 2; kk++)
            offA[m][kk] = row * 128 + (((kk * 4 + lq) ^ (lr & 7)) << 4);
    }
#pragma unroll
    for (int n = 0; n < 4; n++) {
        int row = wn * 64 + n * 16 + lr;
#pragma unroll
        for (int kk = 0; kk < 2; kk++)
            offB[n][kk] = 32768 + row * 128 + (((kk * 4 + lq) ^ (lr & 7)) << 4);
    }

    f32x4 facc[8][4];
#pragma unroll
    for (int m = 0; m < 8; m++)
#pragma unroll
        for (int n = 0; n < 4; n++) facc[m][n] = (f32x4){0.f, 0.f, 0.f, 0.f};

    i32x4 aH[4][2], b[4][2];
    f32x4 sx4[4];
    float swq = 0.f;

    auto LDA = [&](int slot, int mq) {
        const unsigned char* base = lds8 + slot * SLOT_BY + mq * 8192;
#pragma unroll
        for (int m = 0; m < 4; m++)
#pragma unroll
            for (int kk = 0; kk < 2; kk++)
                aH[m][kk] = *reinterpret_cast<const i32x4*>(base + offA[m][kk]);
    };
    auto LDB = [&](int slot) {
        const unsigned char* base = lds8 + slot * SLOT_BY;
#pragma unroll
        for (int n = 0; n < 4; n++)
#pragma unroll
            for (int kk = 0; kk < 2; kk++)
                b[n][kk] = *reinterpret_cast<const i32x4*>(base + offB[n][kk]);
    };
    int sxrow0 = mt * GBM + wm * 128 + lq * 4;
    auto LDSX = [&](int i, int mq) {
#pragma unroll
        for (int m = 0; m < 4; m++)
            sx4[m] = *reinterpret_cast<const f32x4*>(
                sxT + (size_t)i * M + sxrow0 + mq * 64 + m * 16);
    };
    auto MQ = [&](int mq) {
        __builtin_amdgcn_s_setprio(1);
#pragma unroll
        for (int m = 0; m < 4; m++) {
            i32x4 ia[4];
#pragma unroll
            for (int n = 0; n < 4; n++) {
                ia[n] = __builtin_amdgcn_mfma_i32_16x16x64_i8(aH[m][0], b[n][0],
                                                              (i32x4){0, 0, 0, 0}, 0, 0, 0);
                ia[n] = __builtin_amdgcn_mfma_i32_16x16x64_i8(aH[m][1], b[n][1],
                                                              ia[n], 0, 0, 0);
            }
            f32x4 s = sx4[m] * swq;
#pragma unroll
            for (int n = 0; n < 4; n++) {
#pragma unroll
                for (int r = 0; r < 4; r++)
                    facc[mq * 4 + m][n][r] += (float)ia[n][r] * s[r];
            }
        }
        __builtin_amdgcn_s_setprio(0);
    };

    int swbase = (nt * 2 + (wn >> 1)) * nkb;

    // Prologue: stage K-block 0 into slot 0.
    STAGE8(0, 0);
    WAITV(0);
    BAR();

    for (int i = 0; i < nkb; ++i) {
        int p = i & 1, q = p ^ 1;
        int knext = (i + 1 < nkb ? i + 1 : i) * 128;  // clamp keeps vmcnt pattern

        // Load region: scales first, then stages (order pinned for vmcnt(8)).
        LDSX(i, 0);
        swq = swp[swbase + i];
        SCHED0();
        STAGE8(q, knext);
        SCHED0();
        // ds reads: A half 0 + full B (held across both halves).
        LDA(p, 0);
        LDB(p);
        WAITL0();
        WAITV(8);          // forces sxE(+sw); 8 stages keep flying
        MQ(0);
        // Second half: A half 1 (reuses aH) + sxO.
        LDA(p, 1);
        LDSX(i, 1);
        WAITL0();
        WAITV(0);          // forces sxO + stages (stages had ~full half-iter)
        MQ(1);
        BAR();             // publishes slot q stages; orders next iter's writes
    }

    // Epilogue: bias + store. C/D layout: col = lane&15, row = (lane>>4)*4 + reg.
    float bvv[4];
#pragma unroll
    for (int n = 0; n < 4; n++) bvv[n] = bias[nt * GBN + wn * 64 + n * 16 + lr];

#pragma unroll
    for (int m = 0; m < 8; m++) {
#pragma unroll
        for (int r = 0; r < 4; r++) {
            size_t row = (size_t)(mt * GBM + wm * 128 + m * 16 + lq * 4 + r);
            float* Crow = C + row * N + nt * GBN + wn * 64 + lr;
#pragma unroll
            for (int n = 0; n < 4; n++) Crow[n * 16] = facc[m][n][r] + bvv[n];
        }
    }
}

extern "C" void kernel_launch(void* const* d_in, const int* in_sizes, int n_in,
                              void* d_out, int out_size, void* d_ws, size_t ws_size,
                              hipStream_t stream) {
    const float* x = (const float*)d_in[0];
    const float* w = (const float*)d_in[1];
    const float* bias = (const float*)d_in[2];
    float* y = (float*)d_out;

    int O = in_sizes[2];          // 11008
    int K = in_sizes[1] / O;      // 4096
    int T = in_sizes[0] / K;      // 8192 tokens
    int nkb = K / 128;            // 32

    char* qx = (char*)d_ws;
    size_t off = ((size_t)T * K + 255) & ~(size_t)255;
    char* qw = (char*)d_ws + off;
    off += ((size_t)O * K + 255) & ~(size_t)255;
    float* sxT = (float*)((char*)d_ws + off);
    off += ((size_t)nkb * T * 4 + 255) & ~(size_t)255;
    float* sw = (float*)((char*)d_ws + off);

    long ngroups = (long)T * nkb;
    qd_x_kernel<<<dim3((unsigned)((ngroups + 3) / 4)), dim3(256), 0, stream>>>(
        x, qx, sxT, ngroups, nkb, T);
    qd_w_kernel<<<dim3(nkb, O / 128), dim3(256), 0, stream>>>(w, qw, sw, K, nkb);

    int grid = (T / 256) * (O / 256);
    gemm_i8_kernel<<<dim3(grid), dim3(512), 0, stream>>>(qx, qw, sxT, sw, bias, y,
                                                         T, O, K);
}